// Round 1
// baseline (371.064 us; speedup 1.0000x reference)
//
#include <hip/hip_runtime.h>
#include <math.h>

// Tile geometry: 64x16 output pixels per 256-thread block.
#define TX 64
#define TY 16
#define IN_W 72   // TX + 8  (x-halo of 4 on each side keeps float4 alignment; conv needs 3)
#define IN_H 22   // TY + 6  (y-halo of 3 on each side)

struct GaussCoefs {
    float g3[3];
    float g5[5];
    float g7[7];
};

__global__ __launch_bounds__(256) void mgdf_kernel(
    const float* __restrict__ s,
    const float* __restrict__ w1p, const float* __restrict__ w2p,
    const float* __restrict__ w3p, const float* __restrict__ w4p,
    float* __restrict__ out,
    GaussCoefs gc, int Wd, int Hd)
{
    __shared__ float in_tile[IN_H][IN_W];
    __shared__ float h3s[IN_H][TX];
    __shared__ float h5s[IN_H][TX];
    __shared__ float h7s[IN_H][TX];

    const int tid = threadIdx.x;
    const int plane = blockIdx.z;          // b*C + c
    const int x0 = blockIdx.x * TX;
    const int y0 = blockIdx.y * TY;
    const float* sp = s + (size_t)plane * Hd * Wd;

    // Scalar weights (uniform -> s_load); fold the diff chain:
    // w1*s + w2*(s-s3) + w3*(s3-s5) + w4*(s5-s7)
    //  = (w1+w2)*s + (w3-w2)*s3 + (w4-w3)*s5 + (-w4)*s7
    const float w1 = *w1p, w2 = *w2p, w3 = *w3p, w4 = *w4p;
    const float a0 = w1 + w2;
    const float a3 = w3 - w2;
    const float a5 = w4 - w3;
    const float a7 = -w4;

    // ---- Stage input tile (with halo, zero-padded at image borders) ----
    // 396 float4 chunks: 18 per row x 22 rows.
    for (int c = tid; c < (IN_W / 4) * IN_H; c += 256) {
        const int r  = c / (IN_W / 4);
        const int c4 = c % (IN_W / 4);
        const int gy = y0 - 3 + r;
        const int gx = x0 - 4 + c4 * 4;
        float4 v = make_float4(0.f, 0.f, 0.f, 0.f);
        if (gy >= 0 && gy < Hd) {
            const float* rowp = sp + (size_t)gy * Wd;
            if (gx >= 0 && gx + 3 < Wd) {
                v = *(const float4*)(rowp + gx);
            } else {
                float tmp[4];
                #pragma unroll
                for (int j = 0; j < 4; ++j) {
                    const int x = gx + j;
                    tmp[j] = (x >= 0 && x < Wd) ? rowp[x] : 0.f;
                }
                v = make_float4(tmp[0], tmp[1], tmp[2], tmp[3]);
            }
        }
        *(float4*)&in_tile[r][c4 * 4] = v;
    }
    __syncthreads();

    // ---- Horizontal pass: 22 rows x 16 float4 chunks = 352 tasks ----
    for (int task = tid; task < IN_H * (TX / 4); task += 256) {
        const int r  = task / (TX / 4);
        const int ch = task % (TX / 4);
        const float* row = &in_tile[r][ch * 4];
        const float4 va = *(const float4*)(row);
        const float4 vb = *(const float4*)(row + 4);
        const float4 vc = *(const float4*)(row + 8);
        const float v[12] = {va.x, va.y, va.z, va.w,
                             vb.x, vb.y, vb.z, vb.w,
                             vc.x, vc.y, vc.z, vc.w};
        float o3[4], o5[4], o7[4];
        #pragma unroll
        for (int j = 0; j < 4; ++j) {
            // output x = x0 + ch*4 + j -> tile index ch*4 + j + 4 -> v[j+4]
            float h7 = 0.f;
            #pragma unroll
            for (int i = 0; i < 7; ++i) h7 = fmaf(gc.g7[i], v[j + 1 + i], h7);
            float h5 = 0.f;
            #pragma unroll
            for (int i = 0; i < 5; ++i) h5 = fmaf(gc.g5[i], v[j + 2 + i], h5);
            float h3 = 0.f;
            #pragma unroll
            for (int i = 0; i < 3; ++i) h3 = fmaf(gc.g3[i], v[j + 3 + i], h3);
            o3[j] = h3; o5[j] = h5; o7[j] = h7;
        }
        *(float4*)&h3s[r][ch * 4] = make_float4(o3[0], o3[1], o3[2], o3[3]);
        *(float4*)&h5s[r][ch * 4] = make_float4(o5[0], o5[1], o5[2], o5[3]);
        *(float4*)&h7s[r][ch * 4] = make_float4(o7[0], o7[1], o7[2], o7[3]);
    }
    __syncthreads();

    // ---- Vertical pass + fused weighted combine ----
    const int tx = tid & 15;        // 16 float4 chunks across x
    const int ty = tid >> 4;        // 16 output rows
    const int xb = tx * 4;

    float acc3[4] = {0.f, 0.f, 0.f, 0.f};
    float acc5[4] = {0.f, 0.f, 0.f, 0.f};
    float acc7[4] = {0.f, 0.f, 0.f, 0.f};

    #pragma unroll
    for (int i = 0; i < 7; ++i) {
        const float4 hv = *(const float4*)&h7s[ty + i][xb];
        acc7[0] = fmaf(gc.g7[i], hv.x, acc7[0]);
        acc7[1] = fmaf(gc.g7[i], hv.y, acc7[1]);
        acc7[2] = fmaf(gc.g7[i], hv.z, acc7[2]);
        acc7[3] = fmaf(gc.g7[i], hv.w, acc7[3]);
    }
    #pragma unroll
    for (int i = 0; i < 5; ++i) {
        const float4 hv = *(const float4*)&h5s[ty + 1 + i][xb];
        acc5[0] = fmaf(gc.g5[i], hv.x, acc5[0]);
        acc5[1] = fmaf(gc.g5[i], hv.y, acc5[1]);
        acc5[2] = fmaf(gc.g5[i], hv.z, acc5[2]);
        acc5[3] = fmaf(gc.g5[i], hv.w, acc5[3]);
    }
    #pragma unroll
    for (int i = 0; i < 3; ++i) {
        const float4 hv = *(const float4*)&h3s[ty + 2 + i][xb];
        acc3[0] = fmaf(gc.g3[i], hv.x, acc3[0]);
        acc3[1] = fmaf(gc.g3[i], hv.y, acc3[1]);
        acc3[2] = fmaf(gc.g3[i], hv.z, acc3[2]);
        acc3[3] = fmaf(gc.g3[i], hv.w, acc3[3]);
    }

    const float4 sv = *(const float4*)&in_tile[ty + 3][xb + 4];
    float4 o;
    o.x = a0 * sv.x + a3 * acc3[0] + a5 * acc5[0] + a7 * acc7[0];
    o.y = a0 * sv.y + a3 * acc3[1] + a5 * acc5[1] + a7 * acc7[1];
    o.z = a0 * sv.z + a3 * acc3[2] + a5 * acc5[2] + a7 * acc7[2];
    o.w = a0 * sv.w + a3 * acc3[3] + a5 * acc5[3] + a7 * acc7[3];

    float* outp = out + (size_t)plane * Hd * Wd + (size_t)(y0 + ty) * Wd + x0 + xb;
    *(float4*)outp = o;
}

static void fill_gauss(float* g, int k) {
    const double sigma = 0.3 * ((k - 1) * 0.5 - 1.0) + 0.8;
    double t[7], sum = 0.0;
    for (int i = 0; i < k; ++i) {
        const double x = (double)(i - k / 2);
        t[i] = exp(-x * x / (2.0 * sigma * sigma));
        sum += t[i];
    }
    for (int i = 0; i < k; ++i) g[i] = (float)(t[i] / sum);
}

extern "C" void kernel_launch(void* const* d_in, const int* in_sizes, int n_in,
                              void* d_out, int out_size, void* d_ws, size_t ws_size,
                              hipStream_t stream) {
    const float* s  = (const float*)d_in[0];
    const float* w1 = (const float*)d_in[1];
    const float* w2 = (const float*)d_in[2];
    const float* w3 = (const float*)d_in[3];
    const float* w4 = (const float*)d_in[4];
    float* out = (float*)d_out;

    const int Hd = 512, Wd = 512;
    const int planes = in_sizes[0] / (Hd * Wd);   // B*C = 192

    GaussCoefs gc;
    fill_gauss(gc.g3, 3);
    fill_gauss(gc.g5, 5);
    fill_gauss(gc.g7, 7);

    dim3 grid(Wd / TX, Hd / TY, planes);
    mgdf_kernel<<<grid, 256, 0, stream>>>(s, w1, w2, w3, w4, out, gc, Wd, Hd);
}